// Round 10
// baseline (65.636 us; speedup 1.0000x reference)
//
#include <hip/hip_runtime.h>

#define BATCH 8192
#define NUM_SV 8192
#define DIM 256
#define GAMMA 0.1f
#define LOG2E 1.4426950408889634f
// sqrt(2*GAMMA*LOG2E) : pre-scale so MFMA acc == log2-exponent contribution
#define ALPHA 0.53715827f

#define SCHUNK 8              // s-blocks (each block sweeps 1024 sv cols)
#define NST 8                 // s-tiles of 128 per block
#define NKT 4                 // K-tiles of 64
#define BTILE_F16 8192        // B K-tile: 128 cols x 64 k = 16KB

typedef _Float16 f16;
typedef __attribute__((ext_vector_type(8))) _Float16 f16x8;
typedef __attribute__((ext_vector_type(16))) float f32x16;

// ---------------- pre-pass: scaled fp16 copies + norms + dcp ----------------
// x16: plain row-major [row][256]. sv16: per (128-col tile, 64-k tile) 16KB
// block [ks=4][kch=2][col=128][8 f16] -> each lane's B fragment is one
// contiguous f16x8; consecutive lanes contiguous (coalesced direct loads).
__global__ __launch_bounds__(256)
void svm_prep(const float* __restrict__ x, const float* __restrict__ sv,
              const float* __restrict__ dual,
              f16* __restrict__ x16, f16* __restrict__ sv16,
              float* __restrict__ xg, float* __restrict__ dcp) {
  const int id = blockIdx.x * 256 + threadIdx.x;
  const bool isx = id < (BATCH * DIM / 8);
  const int lid = isx ? id : id - (BATCH * DIM / 8);
  const int row = lid >> 5;
  const int k0  = (lid & 31) << 3;

  const float* src = (isx ? x : sv) + (size_t)row * DIM + k0;
  float4 u = *(const float4*)(src);
  float4 v = *(const float4*)(src + 4);

  float sq = u.x*u.x + u.y*u.y + u.z*u.z + u.w*u.w
           + v.x*v.x + v.y*v.y + v.z*v.z + v.w*v.w;
  #pragma unroll
  for (int m = 1; m <= 16; m <<= 1) sq += __shfl_xor(sq, m, 32);
  if ((lid & 31) == 0) {
    float g = -(GAMMA * LOG2E) * sq;
    if (isx) xg[row] = g;
    else     dcp[row] = dual[row] * __builtin_amdgcn_exp2f(g);
  }

  f16x8 h;
  h[0] = (f16)(ALPHA * u.x); h[1] = (f16)(ALPHA * u.y);
  h[2] = (f16)(ALPHA * u.z); h[3] = (f16)(ALPHA * u.w);
  h[4] = (f16)(ALPHA * v.x); h[5] = (f16)(ALPHA * v.y);
  h[6] = (f16)(ALPHA * v.z); h[7] = (f16)(ALPHA * v.w);

  if (isx) {
    *(f16x8*)&x16[(size_t)row * DIM + k0] = h;
  } else {
    const int tile = row >> 7;
    const int col  = row & 127;
    const int kt   = k0 >> 6;
    const int ks   = (k0 >> 4) & 3;
    const int kch  = (k0 >> 3) & 1;
    f16* dst = sv16 + (size_t)(tile * NKT + kt) * BTILE_F16
             + ((ks * 2 + kch) * 128 + col) * 8;
    *(f16x8*)dst = h;
  }
}

// ---------------- main fused MFMA kernel: A in regs, B direct from L2 ------
// 256 threads = 4 waves (wb x wn); wave tile 64x64 as 2x2 of
// mfma_f32_32x32x16_f16. A panel (128 VGPR/wave) loaded once; B fragments
// loaded straight global->VGPR (prepacked, coalesced). NO barriers and NO
// LDS in the main loop: waves free-run, compiler pipelines loads across
// K-tiles, 2 blocks/CU cover each other's latency.
__global__ __launch_bounds__(256, 2)
void svm_main(const f16* __restrict__ x16, const f16* __restrict__ sv16,
              const float* __restrict__ dcp, float* __restrict__ partial) {
  __shared__ float dcpl[NST * 128];    // 4KB
  __shared__ float red[2][128];

  const int tid = threadIdx.x;
  const int w   = tid >> 6;
  const int l   = tid & 63;
  const int lr  = l & 31;
  const int lh  = l >> 5;
  const int wb  = w >> 1;
  const int wn  = w & 1;

  // bijective XCD remap: each XCD gets a 16(bt) x 2(sch) rectangle
  const int bid = blockIdx.x;
  const int q   = bid & 7;
  const int idx = bid >> 3;
  const int bt  = (q & 3) * 16 + (idx & 15);    // 0..63
  const int sch = (q >> 2) * 4 + (idx >> 4);    // 0..7

  *(float4*)&dcpl[tid * 4] = *(const float4*)&dcp[sch * 1024 + tid * 4];

  // ---- A panel -> registers (once); static indices only ----
  f16x8 af[2][16];
  {
    const f16* xb = x16 + (size_t)(bt * 128 + wb * 64 + lr) * DIM + lh * 8;
    #pragma unroll
    for (int m = 0; m < 2; ++m)
      #pragma unroll
      for (int kk = 0; kk < 16; ++kk)
        af[m][kk] = *(const f16x8*)&xb[m * 32 * DIM + kk * 16];
  }
  __syncthreads();   // dcpl published (also the last block-wide sync til reduce)

  float ctr[2][16];
  #pragma unroll
  for (int m = 0; m < 2; ++m)
    #pragma unroll
    for (int r = 0; r < 16; ++r) ctr[m][r] = 0.f;

  // per-lane base into a B K-tile: fragment (ks,kch=lh,col=wn*64+lr)
  const int boff = (lh * 128 + wn * 64 + lr) * 8;

  #pragma unroll 1
  for (int st = 0; st < NST; ++st) {
    const f16* bbase = sv16 + (size_t)((sch * NST + st) * NKT) * BTILE_F16 + boff;

    f32x16 acc[2][2];
    #pragma unroll
    for (int m = 0; m < 2; ++m)
      #pragma unroll
      for (int n = 0; n < 2; ++n)
        #pragma unroll
        for (int r = 0; r < 16; ++r) acc[m][n][r] = 0.f;

    #pragma unroll              // kt fully unrolled: af index static (rule #20)
    for (int kt = 0; kt < NKT; ++kt) {
      const f16* bb = bbase + kt * BTILE_F16;
      #pragma unroll
      for (int ks = 0; ks < 4; ++ks) {
        f16x8 b0 = *(const f16x8*)&bb[ks * 2048];            // col block +0
        f16x8 b1 = *(const f16x8*)&bb[ks * 2048 + 32 * 8];   // col block +32
        acc[0][0] = __builtin_amdgcn_mfma_f32_32x32x16_f16(af[0][kt * 4 + ks], b0, acc[0][0], 0, 0, 0);
        acc[0][1] = __builtin_amdgcn_mfma_f32_32x32x16_f16(af[0][kt * 4 + ks], b1, acc[0][1], 0, 0, 0);
        acc[1][0] = __builtin_amdgcn_mfma_f32_32x32x16_f16(af[1][kt * 4 + ks], b0, acc[1][0], 0, 0, 0);
        acc[1][1] = __builtin_amdgcn_mfma_f32_32x32x16_f16(af[1][kt * 4 + ks], b1, acc[1][1], 0, 0, 0);
      }
    }

    // ---- fused epilogue for s-tile st (regs + dcpl LDS reads only)
    #pragma unroll
    for (int n = 0; n < 2; ++n) {
      const float dv = dcpl[st * 128 + wn * 64 + n * 32 + lr];
      #pragma unroll
      for (int m = 0; m < 2; ++m)
        #pragma unroll
        for (int r = 0; r < 16; ++r)
          ctr[m][r] = fmaf(__builtin_amdgcn_exp2f(acc[m][n][r]), dv, ctr[m][r]);
    }
  }

  // ---- reduce ctr across the 32 col-lanes sharing each row set
  #pragma unroll
  for (int m = 0; m < 2; ++m)
    #pragma unroll
    for (int r = 0; r < 16; ++r) {
      float v = ctr[m][r];
      v += __shfl_xor(v, 1, 64);
      v += __shfl_xor(v, 2, 64);
      v += __shfl_xor(v, 4, 64);
      v += __shfl_xor(v, 8, 64);
      v += __shfl_xor(v, 16, 64);
      ctr[m][r] = v;
    }

  __syncthreads();
  if (lr == 0) {
    #pragma unroll
    for (int m = 0; m < 2; ++m)
      #pragma unroll
      for (int r = 0; r < 16; ++r) {
        const int rl = wb * 64 + m * 32 + (r & 3) + 8 * (r >> 2) + 4 * lh;
        red[wn][rl] = ctr[m][r];
      }
  }
  __syncthreads();
  if (tid < 128)
    partial[(size_t)sch * BATCH + bt * 128 + tid] = red[0][tid] + red[1][tid];
}

// ---------------- final reduction + x-norm factor ----------------
__global__ __launch_bounds__(256)
void svm_reduce(const float* __restrict__ partial, const float* __restrict__ xg,
                float* __restrict__ out) {
  const int b = blockIdx.x * 256 + threadIdx.x;
  float s = 0.f;
  #pragma unroll
  for (int c = 0; c < SCHUNK; ++c) s += partial[(size_t)c * BATCH + b];
  out[b] = __builtin_amdgcn_exp2f(xg[b]) * s;
}

extern "C" void kernel_launch(void* const* d_in, const int* in_sizes, int n_in,
                              void* d_out, int out_size, void* d_ws, size_t ws_size,
                              hipStream_t stream) {
  const float* x    = (const float*)d_in[0];
  const float* sv   = (const float*)d_in[1];
  const float* dual = (const float*)d_in[2];
  float* out = (float*)d_out;

  f16*   x16     = (f16*)d_ws;                       // 4MB
  f16*   sv16    = x16 + (size_t)BATCH * DIM;        // 4MB
  float* xg      = (float*)(sv16 + (size_t)NUM_SV * DIM);
  float* dcp     = xg + BATCH;
  float* partial = dcp + NUM_SV;                     // SCHUNK * BATCH

  svm_prep<<<(BATCH + NUM_SV) * DIM / 8 / 256, 256, 0, stream>>>(x, sv, dual, x16, sv16, xg, dcp);
  svm_main<<<(BATCH / 128) * SCHUNK, 256, 0, stream>>>(x16, sv16, dcp, partial);
  svm_reduce<<<BATCH / 256, 256, 0, stream>>>(partial, xg, out);
}

// Round 11
// 60.624 us; speedup vs baseline: 1.0827x; 1.0827x over previous
//
#include <hip/hip_runtime.h>

#define BATCH 8192
#define NUM_SV 8192
#define DIM 256
#define GAMMA 0.1f
#define LOG2E 1.4426950408889634f
// sqrt(2*GAMMA*LOG2E) : pre-scale so MFMA acc == log2-exponent contribution
#define ALPHA 0.53715827f

#define SCHUNK 8              // s-chunks of 1024 cols
#define NST 8                 // s-tiles of 128 per block
#define NKT 4                 // K-tiles of 64
#define NITER (NST * NKT)     // 32

typedef _Float16 f16;
typedef __attribute__((ext_vector_type(8))) _Float16 f16x8;
typedef __attribute__((ext_vector_type(16))) float f32x16;

__device__ __forceinline__ void gload_lds16(const f16* g, f16* l) {
  __builtin_amdgcn_global_load_lds((const __attribute__((address_space(1))) void*)g,
                                   (__attribute__((address_space(3))) void*)l, 16, 0, 0);
}

// ---------------- pre-pass: scaled fp16 copies + norms + dcp ----------------
// x16: row-major [row][256]. sv16: per-(64-col tile, 64-k tile) 8KB block of
// 8 slabs [slab = ks*2+kch][col=64][8 f16]; each 1KB slab is one lane-linear
// global_load_lds DMA and one conflict-free ds_read_b128 fragment set.
__global__ __launch_bounds__(256)
void svm_prep(const float* __restrict__ x, const float* __restrict__ sv,
              const float* __restrict__ dual,
              f16* __restrict__ x16, f16* __restrict__ sv16,
              float* __restrict__ xg, float* __restrict__ dcp) {
  const int id = blockIdx.x * 256 + threadIdx.x;
  const bool isx = id < (BATCH * DIM / 8);
  const int lid = isx ? id : id - (BATCH * DIM / 8);
  const int row = lid >> 5;
  const int k0  = (lid & 31) << 3;

  const float* src = (isx ? x : sv) + (size_t)row * DIM + k0;
  float4 u = *(const float4*)(src);
  float4 v = *(const float4*)(src + 4);

  float sq = u.x*u.x + u.y*u.y + u.z*u.z + u.w*u.w
           + v.x*v.x + v.y*v.y + v.z*v.z + v.w*v.w;
  #pragma unroll
  for (int m = 1; m <= 16; m <<= 1) sq += __shfl_xor(sq, m, 32);
  if ((lid & 31) == 0) {
    float g = -(GAMMA * LOG2E) * sq;
    if (isx) xg[row] = g;
    else     dcp[row] = dual[row] * __builtin_amdgcn_exp2f(g);
  }

  f16x8 h;
  h[0] = (f16)(ALPHA * u.x); h[1] = (f16)(ALPHA * u.y);
  h[2] = (f16)(ALPHA * u.z); h[3] = (f16)(ALPHA * u.w);
  h[4] = (f16)(ALPHA * v.x); h[5] = (f16)(ALPHA * v.y);
  h[6] = (f16)(ALPHA * v.z); h[7] = (f16)(ALPHA * v.w);

  if (isx) {
    *(f16x8*)&x16[(size_t)row * DIM + k0] = h;
  } else {
    const int tile64 = row >> 6;          // 64-col sv tile 0..127
    const int col    = row & 63;
    const int kt     = k0 >> 6;           // K-tile of 64
    const int ks     = (k0 >> 4) & 3;     // 16-k slice
    const int kch    = (k0 >> 3) & 1;     // 8-k half (lh)
    f16* dst = sv16 + (size_t)((tile64 * NKT + kt) * 8 + ks * 2 + kch) * 512
             + col * 8;
    *(f16x8*)dst = h;
  }
}

// ---------------- main fused MFMA kernel: wave-private async pipeline -------
// 256 threads = 4 waves (wb x wn); wave tile 64x64 as 2x2 of
// mfma_f32_32x32x16_f16. A panel (128 VGPR) in registers; each wave DMAs its
// OWN 8KB B tile (64 cols x 64 k) via global_load_lds, double-buffered,
// 2-deep prefetch, gated by wave-local s_waitcnt vmcnt — NO barriers in the
// main loop at all. 2 blocks/CU.
__global__ __launch_bounds__(256, 2)
void svm_main(const f16* __restrict__ x16, const f16* __restrict__ sv16,
              const float* __restrict__ dcp, float* __restrict__ partial) {
  __shared__ f16 bstage[4][2][4096];   // [wave][buf][8KB] = 64KB
  __shared__ float dcpl[1024];         // 4KB
  __shared__ float red[2][128];

  const int tid = threadIdx.x;
  const int w   = tid >> 6;
  const int l   = tid & 63;
  const int lr  = l & 31;
  const int lh  = l >> 5;
  const int wb  = w >> 1;
  const int wn  = w & 1;

  // bijective XCD remap: each XCD gets a 16(bt) x 2(sch) rectangle
  const int bid = blockIdx.x;
  const int q   = bid & 7;
  const int idx = bid >> 3;
  const int bt  = (q & 3) * 16 + (idx & 15);    // 0..63
  const int sch = (q >> 2) * 4 + (idx >> 4);    // 0..7

  *(float4*)&dcpl[tid * 4] = *(const float4*)&dcp[sch * 1024 + tid * 4];

  // ---- A panel -> registers (once); static indices only ----
  f16x8 af[2][16];
  {
    const f16* xb = x16 + (size_t)(bt * 128 + wb * 64 + lr) * DIM + lh * 8;
    #pragma unroll
    for (int m = 0; m < 2; ++m)
      #pragma unroll
      for (int kk = 0; kk < 16; ++kk)
        af[m][kk] = *(const f16x8*)&xb[m * 32 * DIM + kk * 16];
  }
  __syncthreads();   // dcpl published; all prologue VMEM drained

  // wave-private stage of B tile for global step t (st=t>>2, kt=t&3); parity
  // passed as a literal so the LDS buffer index is compile-time (rule #20).
  auto stage = [&](int t, int par) {
    const int st = t >> 2, kt = t & 3;
    const int tile64 = (sch * NST + st) * 2 + wn;
    const f16* src = sv16 + (size_t)((tile64 * NKT + kt) * 8) * 512 + l * 8;
    f16* dst = &bstage[w][par][0];
    #pragma unroll
    for (int i = 0; i < 8; ++i)
      gload_lds16(src + i * 512, dst + i * 512);
  };

  float ctr[2][16];
  #pragma unroll
  for (int m = 0; m < 2; ++m)
    #pragma unroll
    for (int r = 0; r < 16; ++r) ctr[m][r] = 0.f;

  stage(0, 0);
  stage(1, 1);

  #pragma unroll 1
  for (int st = 0; st < NST; ++st) {
    f32x16 acc[2][2];
    #pragma unroll
    for (int m = 0; m < 2; ++m)
      #pragma unroll
      for (int n = 0; n < 2; ++n)
        #pragma unroll
        for (int r = 0; r < 16; ++r) acc[m][n][r] = 0.f;

    #pragma unroll              // kt fully unrolled: af index + parity static
    for (int kt = 0; kt < NKT; ++kt) {
      const int t = st * NKT + kt;
      // wave-local gate: tile t landed (tile t+1 stays in flight)
      if (t < NITER - 1)
        asm volatile("s_waitcnt vmcnt(8)" ::: "memory");
      else
        asm volatile("s_waitcnt vmcnt(0)" ::: "memory");

      const f16* buf = &bstage[w][kt & 1][0];
      #pragma unroll
      for (int ks = 0; ks < 4; ++ks) {
        f16x8 b0 = *(const f16x8*)&buf[(ks * 2 + lh) * 512 + lr * 8];
        f16x8 b1 = *(const f16x8*)&buf[(ks * 2 + lh) * 512 + (32 + lr) * 8];
        acc[0][0] = __builtin_amdgcn_mfma_f32_32x32x16_f16(af[0][kt * 4 + ks], b0, acc[0][0], 0, 0, 0);
        acc[0][1] = __builtin_amdgcn_mfma_f32_32x32x16_f16(af[0][kt * 4 + ks], b1, acc[0][1], 0, 0, 0);
        acc[1][0] = __builtin_amdgcn_mfma_f32_32x32x16_f16(af[1][kt * 4 + ks], b0, acc[1][0], 0, 0, 0);
        acc[1][1] = __builtin_amdgcn_mfma_f32_32x32x16_f16(af[1][kt * 4 + ks], b1, acc[1][1], 0, 0, 0);
      }

      // all reads of this buffer retired -> safe to DMA-overwrite its parity
      asm volatile("s_waitcnt lgkmcnt(0)" ::: "memory");
      __builtin_amdgcn_sched_barrier(0);
      if (t + 2 < NITER) stage(t + 2, kt & 1);
    }

    // ---- fused epilogue for s-tile st (regs + dcpl LDS reads only)
    #pragma unroll
    for (int n = 0; n < 2; ++n) {
      const float dv = dcpl[st * 128 + wn * 64 + n * 32 + lr];
      #pragma unroll
      for (int m = 0; m < 2; ++m)
        #pragma unroll
        for (int r = 0; r < 16; ++r)
          ctr[m][r] = fmaf(__builtin_amdgcn_exp2f(acc[m][n][r]), dv, ctr[m][r]);
    }
  }

  // ---- reduce ctr across the 32 col-lanes sharing each row set
  #pragma unroll
  for (int m = 0; m < 2; ++m)
    #pragma unroll
    for (int r = 0; r < 16; ++r) {
      float v = ctr[m][r];
      v += __shfl_xor(v, 1, 64);
      v += __shfl_xor(v, 2, 64);
      v += __shfl_xor(v, 4, 64);
      v += __shfl_xor(v, 8, 64);
      v += __shfl_xor(v, 16, 64);
      ctr[m][r] = v;
    }

  __syncthreads();
  if (lr == 0) {
    #pragma unroll
    for (int m = 0; m < 2; ++m)
      #pragma unroll
      for (int r = 0; r < 16; ++r) {
        const int rl = wb * 64 + m * 32 + (r & 3) + 8 * (r >> 2) + 4 * lh;
        red[wn][rl] = ctr[m][r];
      }
  }
  __syncthreads();
  if (tid < 128)
    partial[(size_t)sch * BATCH + bt * 128 + tid] = red[0][tid] + red[1][tid];
}

// ---------------- final reduction + x-norm factor ----------------
__global__ __launch_bounds__(256)
void svm_reduce(const float* __restrict__ partial, const float* __restrict__ xg,
                float* __restrict__ out) {
  const int b = blockIdx.x * 256 + threadIdx.x;
  float s = 0.f;
  #pragma unroll
  for (int c = 0; c < SCHUNK; ++c) s += partial[(size_t)c * BATCH + b];
  out[b] = __builtin_amdgcn_exp2f(xg[b]) * s;
}

extern "C" void kernel_launch(void* const* d_in, const int* in_sizes, int n_in,
                              void* d_out, int out_size, void* d_ws, size_t ws_size,
                              hipStream_t stream) {
  const float* x    = (const float*)d_in[0];
  const float* sv   = (const float*)d_in[1];
  const float* dual = (const float*)d_in[2];
  float* out = (float*)d_out;

  f16*   x16     = (f16*)d_ws;                       // 4MB
  f16*   sv16    = x16 + (size_t)BATCH * DIM;        // 4MB
  float* xg      = (float*)(sv16 + (size_t)NUM_SV * DIM);
  float* dcp     = xg + BATCH;
  float* partial = dcp + NUM_SV;                     // SCHUNK * BATCH

  svm_prep<<<(BATCH + NUM_SV) * DIM / 8 / 256, 256, 0, stream>>>(x, sv, dual, x16, sv16, xg, dcp);
  svm_main<<<(BATCH / 128) * SCHUNK, 256, 0, stream>>>(x16, sv16, dcp, partial);
  svm_reduce<<<BATCH / 256, 256, 0, stream>>>(partial, xg, out);
}